// Round 11
// baseline (259.672 us; speedup 1.0000x reference)
//
#include <hip/hip_runtime.h>

// GCN autoencoder: recon = (Z @ Z^T)
//   h  = X @ W1                (10000x512 @ 512x32)
//   h1 = A @ h                 (edge-parallel atomic SpMM, raw sums)
//   g  = A @ relu(h1)          (same pattern, relu applied at gather)
//   z  = g @ W2                (ASSOCIATIVITY: A(relu(h1)W2) = (A relu(h1))W2)
//        computed on-the-fly in zzt's staging prologue (never materialized)
//   out= z @ z^T               (400 MB store-bound, ~58 us floor)
//
// R11: R10 ledger = 80us node overhead (5x16, 41%!) + front 34 + zzt 81.
// Associativity kills the ELL build AND spmm2's separate node: 4 nodes.
//   K1 xw1 + zero(h1|g)    K2 spmm1 atomic (R2-proven ~10us pattern)
//   K3 spmm_g atomic (+relu at read)
//   K4 zzt, z = g@W2 fused into staging: each thread's W2 col-quad is
//      thread-invariant (kq=(t&3)*4 for all 5 staging tasks) -> 32x float4
//      W2 preload in regs, per task 8 g-loads + 128 reg-FMA. Main loop =
//      EXACT R10 (64x256 tile, 8x8/thread, nontemporal stores).

constexpr int N_   = 10000;
constexpr int E_   = 320000;
constexpr int F_   = 512;
constexpr int H1_  = 32;
constexpr int H2_  = 16;

typedef float f32x4 __attribute__((ext_vector_type(4)));

// ---------------- K1: h = X @ W1, side blocks zero h1|g ----------------
constexpr int GEMM_BLOCKS = (N_ * H1_) / 256;                 // 1250
constexpr int ZERO_FLOATS = 2 * N_ * H1_;                     // h1|g adjacent
constexpr int ZERO_BLOCKS = (ZERO_FLOATS / 4 + 255) / 256;    // 625

__global__ __launch_bounds__(256) void gemm_xw1_zero(const float* __restrict__ x,
                                                     const float* __restrict__ W1,
                                                     float* __restrict__ h,
                                                     float4* __restrict__ zero_base) {
    if (blockIdx.x >= GEMM_BLOCKS) {
        int i = (blockIdx.x - GEMM_BLOCKS) * 256 + threadIdx.x;
        if (i < ZERO_FLOATS / 4) zero_base[i] = make_float4(0.f, 0.f, 0.f, 0.f);
        return;
    }
    int tid = blockIdx.x * blockDim.x + threadIdx.x;
    int r = tid >> 5;          // /32
    int c = tid & (H1_ - 1);
    const float4* xr = reinterpret_cast<const float4*>(x + (size_t)r * F_);
    float acc = 0.f;
#pragma unroll 8
    for (int k4 = 0; k4 < F_ / 4; ++k4) {
        float4 xv = xr[k4];
        int k = k4 * 4;
        acc = fmaf(xv.x, W1[(k + 0) * H1_ + c], acc);
        acc = fmaf(xv.y, W1[(k + 1) * H1_ + c], acc);
        acc = fmaf(xv.z, W1[(k + 2) * H1_ + c], acc);
        acc = fmaf(xv.w, W1[(k + 3) * H1_ + c], acc);
    }
    h[tid] = acc;
}

// ---------------- K2: h1[r] += w * h[c]  (edge-parallel, 32 lanes/edge) ----
__global__ __launch_bounds__(256) void spmm1_atomic(const float* __restrict__ h,
                                                    const float* __restrict__ ew,
                                                    const int* __restrict__ erow,
                                                    const int* __restrict__ ecol,
                                                    float* __restrict__ h1) {
    int tid = blockIdx.x * blockDim.x + threadIdx.x;
    if (tid >= E_ * H1_) return;
    int e = tid >> 5;
    int f = tid & (H1_ - 1);
    int r = erow[e];
    int c = ecol[e];
    atomicAdd(&h1[(size_t)r * H1_ + f], ew[e] * h[(size_t)c * H1_ + f]);
}

// ---------------- K3: g[r] += w * relu(h1[c])  (edge-parallel) -------------
__global__ __launch_bounds__(256) void spmm_g(const float* __restrict__ h1,
                                              const float* __restrict__ ew,
                                              const int* __restrict__ erow,
                                              const int* __restrict__ ecol,
                                              float* __restrict__ g) {
    int tid = blockIdx.x * blockDim.x + threadIdx.x;
    if (tid >= E_ * H1_) return;
    int e = tid >> 5;
    int f = tid & (H1_ - 1);
    int r = erow[e];
    int c = ecol[e];
    atomicAdd(&g[(size_t)r * H1_ + f],
              ew[e] * fmaxf(h1[(size_t)c * H1_ + f], 0.f));
}

// ---------------- K4: out = z @ z^T with z = g @ W2 in prologue ------------
constexpr int BI = 64;
constexpr int BJ = 256;

__global__ __launch_bounds__(256) void zzt_w2(const float* __restrict__ g,
                                              const float* __restrict__ W2,
                                              float* __restrict__ out) {
    __shared__ float zi[H2_][BI + 4];    // 16 x 68
    __shared__ float zj[H2_][BJ + 8];    // 16 x 264
    const int t  = threadIdx.x;
    const int ib = blockIdx.y * BI;
    const int jb = blockIdx.x * BJ;
    const int kq = (t & 3) * 4;          // thread-invariant W2 column quad

    // W2 columns kq..kq+3 -> registers (32 x float4, broadcast loads)
    float4 w2r[H1_];
#pragma unroll
    for (int k = 0; k < H1_; ++k)
        w2r[k] = *reinterpret_cast<const float4*>(W2 + k * H2_ + kq);

    // stage zi: row = t>>2; z[gr][kq..kq+3] = g[gr][:] @ W2[:][kq..kq+3]
    {
        int row = t >> 2;
        int gr  = ib + row;
        float4 zv = make_float4(0.f, 0.f, 0.f, 0.f);
        if (gr < N_) {
            const float4* grow = reinterpret_cast<const float4*>(g + (size_t)gr * H1_);
#pragma unroll
            for (int k4 = 0; k4 < H1_ / 4; ++k4) {
                float4 g4 = grow[k4];
                const float4 w0 = w2r[k4 * 4 + 0], w1 = w2r[k4 * 4 + 1];
                const float4 w2v = w2r[k4 * 4 + 2], w3 = w2r[k4 * 4 + 3];
                zv.x = fmaf(g4.x, w0.x, zv.x); zv.y = fmaf(g4.x, w0.y, zv.y);
                zv.z = fmaf(g4.x, w0.z, zv.z); zv.w = fmaf(g4.x, w0.w, zv.w);
                zv.x = fmaf(g4.y, w1.x, zv.x); zv.y = fmaf(g4.y, w1.y, zv.y);
                zv.z = fmaf(g4.y, w1.z, zv.z); zv.w = fmaf(g4.y, w1.w, zv.w);
                zv.x = fmaf(g4.z, w2v.x, zv.x); zv.y = fmaf(g4.z, w2v.y, zv.y);
                zv.z = fmaf(g4.z, w2v.z, zv.z); zv.w = fmaf(g4.z, w2v.w, zv.w);
                zv.x = fmaf(g4.w, w3.x, zv.x); zv.y = fmaf(g4.w, w3.y, zv.y);
                zv.z = fmaf(g4.w, w3.z, zv.z); zv.w = fmaf(g4.w, w3.w, zv.w);
            }
        }
        zi[kq + 0][row] = zv.x;
        zi[kq + 1][row] = zv.y;
        zi[kq + 2][row] = zv.z;
        zi[kq + 3][row] = zv.w;
    }
    // stage zj: 256 rows, 4 iterations (idx&3 == t&3, so kq matches w2r)
#pragma unroll
    for (int it = 0; it < 4; ++it) {
        int idx = it * 256 + t;
        int row = idx >> 2;
        int gr  = jb + row;
        float4 zv = make_float4(0.f, 0.f, 0.f, 0.f);
        if (gr < N_) {
            const float4* grow = reinterpret_cast<const float4*>(g + (size_t)gr * H1_);
#pragma unroll
            for (int k4 = 0; k4 < H1_ / 4; ++k4) {
                float4 g4 = grow[k4];
                const float4 w0 = w2r[k4 * 4 + 0], w1 = w2r[k4 * 4 + 1];
                const float4 w2v = w2r[k4 * 4 + 2], w3 = w2r[k4 * 4 + 3];
                zv.x = fmaf(g4.x, w0.x, zv.x); zv.y = fmaf(g4.x, w0.y, zv.y);
                zv.z = fmaf(g4.x, w0.z, zv.z); zv.w = fmaf(g4.x, w0.w, zv.w);
                zv.x = fmaf(g4.y, w1.x, zv.x); zv.y = fmaf(g4.y, w1.y, zv.y);
                zv.z = fmaf(g4.y, w1.z, zv.z); zv.w = fmaf(g4.y, w1.w, zv.w);
                zv.x = fmaf(g4.z, w2v.x, zv.x); zv.y = fmaf(g4.z, w2v.y, zv.y);
                zv.z = fmaf(g4.z, w2v.z, zv.z); zv.w = fmaf(g4.z, w2v.w, zv.w);
                zv.x = fmaf(g4.w, w3.x, zv.x); zv.y = fmaf(g4.w, w3.y, zv.y);
                zv.z = fmaf(g4.w, w3.z, zv.z); zv.w = fmaf(g4.w, w3.w, zv.w);
            }
        }
        zj[kq + 0][row] = zv.x;
        zj[kq + 1][row] = zv.y;
        zj[kq + 2][row] = zv.z;
        zj[kq + 3][row] = zv.w;
    }
    __syncthreads();

    const int tj = t & 31;          // 32 j-lanes
    const int i0 = (t >> 5) * 8;    // 8 i-groups of 8 rows

    float4 accA[8] = {};            // j = jb + tj*4 .. +3
    float4 accB[8] = {};            // j = jb + 128 + tj*4 .. +3

#pragma unroll
    for (int k = 0; k < H2_; ++k) {
        float4 b0 = *reinterpret_cast<const float4*>(&zj[k][tj * 4]);
        float4 b1 = *reinterpret_cast<const float4*>(&zj[k][128 + tj * 4]);
        float4 a0 = *reinterpret_cast<const float4*>(&zi[k][i0]);      // bcast
        float4 a1 = *reinterpret_cast<const float4*>(&zi[k][i0 + 4]);  // bcast
        float av[8] = {a0.x, a0.y, a0.z, a0.w, a1.x, a1.y, a1.z, a1.w};
#pragma unroll
        for (int ii = 0; ii < 8; ++ii) {
            accA[ii].x = fmaf(av[ii], b0.x, accA[ii].x);
            accA[ii].y = fmaf(av[ii], b0.y, accA[ii].y);
            accA[ii].z = fmaf(av[ii], b0.z, accA[ii].z);
            accA[ii].w = fmaf(av[ii], b0.w, accA[ii].w);
            accB[ii].x = fmaf(av[ii], b1.x, accB[ii].x);
            accB[ii].y = fmaf(av[ii], b1.y, accB[ii].y);
            accB[ii].z = fmaf(av[ii], b1.z, accB[ii].z);
            accB[ii].w = fmaf(av[ii], b1.w, accB[ii].w);
        }
    }

    const int j0 = jb + tj * 4;
    const int j1 = jb + 128 + tj * 4;
#pragma unroll
    for (int ii = 0; ii < 8; ++ii) {
        int gi = ib + i0 + ii;
        if (gi >= N_) break;
        float* orow = out + (size_t)gi * N_;
        if (j0 + 3 < N_) {
            f32x4 v = {accA[ii].x, accA[ii].y, accA[ii].z, accA[ii].w};
            __builtin_nontemporal_store(v, reinterpret_cast<f32x4*>(orow + j0));
        } else {
            float a[4] = {accA[ii].x, accA[ii].y, accA[ii].z, accA[ii].w};
            for (int jj = 0; jj < 4; ++jj)
                if (j0 + jj < N_) orow[j0 + jj] = a[jj];
        }
        if (j1 + 3 < N_) {
            f32x4 v = {accB[ii].x, accB[ii].y, accB[ii].z, accB[ii].w};
            __builtin_nontemporal_store(v, reinterpret_cast<f32x4*>(orow + j1));
        } else {
            float b[4] = {accB[ii].x, accB[ii].y, accB[ii].z, accB[ii].w};
            for (int jj = 0; jj < 4; ++jj)
                if (j1 + jj < N_) orow[j1 + jj] = b[jj];
        }
    }
}

extern "C" void kernel_launch(void* const* d_in, const int* in_sizes, int n_in,
                              void* d_out, int out_size, void* d_ws, size_t ws_size,
                              hipStream_t stream) {
    const float* x    = (const float*)d_in[0];
    const float* ew   = (const float*)d_in[1];
    const float* W1   = (const float*)d_in[2];
    const float* W2   = (const float*)d_in[3];
    const int*   erow = (const int*)d_in[4];
    const int*   ecol = (const int*)d_in[5];
    float* out = (float*)d_out;

    // workspace (4B elems): h | h1 | g   (h1,g adjacent -> one zero range)
    float* h  = (float*)d_ws;               // N*H1
    float* h1 = h  + (size_t)N_ * H1_;      // N*H1  (atomic target)
    float* g  = h1 + (size_t)N_ * H1_;      // N*H1  (atomic target)

    gemm_xw1_zero<<<GEMM_BLOCKS + ZERO_BLOCKS, 256, 0, stream>>>(
        x, W1, h, (float4*)h1);
    spmm1_atomic<<<(E_ * H1_ + 255) / 256, 256, 0, stream>>>(h, ew, erow, ecol, h1);
    spmm_g<<<(E_ * H1_ + 255) / 256, 256, 0, stream>>>(h1, ew, erow, ecol, g);

    dim3 grid((N_ + BJ - 1) / BJ, (N_ + BI - 1) / BI);   // 40 x 157
    zzt_w2<<<grid, 256, 0, stream>>>(g, W2, out);
}

// Round 12
// 227.072 us; speedup vs baseline: 1.1436x; 1.1436x over previous
//
#include <hip/hip_runtime.h>

// GCN autoencoder: recon = (Z @ Z^T)
//   h  = X @ W1            (10000x512 @ 512x32)
//   h1 = A @ h             (edge-parallel atomic SpMM, raw sums)
//   z  = A @ (relu(h1)@W2) (edge-parallel atomic, W2-col in 32 lane-regs)
//   out= z @ z^T           (400 MB store-bound, ~58 us floor)
//
// R12. R8+R11 post-mortem: both regressions were zzt VGPR explosions
// (>=150 VGPR halves waves -> store-bound kernel loses store parallelism
// -> 81us becomes ~160us). Rule: zzt stays <=~100 VGPR -> zzt = EXACT R10.
// Node cut taken on the front instead (R2 data bounds atomic-SpMM exec at
// ~20us combined): 4 nodes = gemm+zero(h1|z) -> spmm1 -> spmm2_mlp -> zzt.
// spmm2_mlp: lane f holds W2[:,f] in 32 VGPRs (coalesced preload), h1-row
// read as broadcast float4, no LDS in loop, 1 atomic/thread. ~60 VGPR.

constexpr int N_   = 10000;
constexpr int E_   = 320000;
constexpr int F_   = 512;
constexpr int H1_  = 32;
constexpr int H2_  = 16;

typedef float f32x4 __attribute__((ext_vector_type(4)));

// ---------------- K1: h = X @ W1, side blocks zero h1|z ----------------
constexpr int GEMM_BLOCKS = (N_ * H1_) / 256;                 // 1250
constexpr int ZERO_FLOATS = N_ * (H1_ + H2_);                 // h1|z adjacent
constexpr int ZERO_BLOCKS = (ZERO_FLOATS / 4 + 255) / 256;    // 469

__global__ __launch_bounds__(256) void gemm_xw1_zero(const float* __restrict__ x,
                                                     const float* __restrict__ W1,
                                                     float* __restrict__ h,
                                                     float4* __restrict__ zero_base) {
    if (blockIdx.x >= GEMM_BLOCKS) {
        int i = (blockIdx.x - GEMM_BLOCKS) * 256 + threadIdx.x;
        if (i < ZERO_FLOATS / 4) zero_base[i] = make_float4(0.f, 0.f, 0.f, 0.f);
        return;
    }
    int tid = blockIdx.x * blockDim.x + threadIdx.x;
    int r = tid >> 5;          // /32
    int c = tid & (H1_ - 1);
    const float4* xr = reinterpret_cast<const float4*>(x + (size_t)r * F_);
    float acc = 0.f;
#pragma unroll 8
    for (int k4 = 0; k4 < F_ / 4; ++k4) {
        float4 xv = xr[k4];
        int k = k4 * 4;
        acc = fmaf(xv.x, W1[(k + 0) * H1_ + c], acc);
        acc = fmaf(xv.y, W1[(k + 1) * H1_ + c], acc);
        acc = fmaf(xv.z, W1[(k + 2) * H1_ + c], acc);
        acc = fmaf(xv.w, W1[(k + 3) * H1_ + c], acc);
    }
    h[tid] = acc;
}

// ---------------- K2: h1[r] += w * h[c]  (edge-parallel, 32 lanes/edge) ----
__global__ __launch_bounds__(256) void spmm1_atomic(const float* __restrict__ h,
                                                    const float* __restrict__ ew,
                                                    const int* __restrict__ erow,
                                                    const int* __restrict__ ecol,
                                                    float* __restrict__ h1) {
    int tid = blockIdx.x * blockDim.x + threadIdx.x;
    if (tid >= E_ * H1_) return;
    int e = tid >> 5;
    int f = tid & (H1_ - 1);
    int r = erow[e];
    int c = ecol[e];
    atomicAdd(&h1[(size_t)r * H1_ + f], ew[e] * h[(size_t)c * H1_ + f]);
}

// ---------------- K3: z[r][f] += w * (relu(h1[c]) . W2[:,f]) ---------------
__global__ __launch_bounds__(256) void spmm2_mlp(const float* __restrict__ h1,
                                                 const float* __restrict__ W2,
                                                 const float* __restrict__ ew,
                                                 const int* __restrict__ erow,
                                                 const int* __restrict__ ecol,
                                                 float* __restrict__ z) {
    int tid = blockIdx.x * blockDim.x + threadIdx.x;
    if (tid >= E_ * H2_) return;
    int e = tid >> 4;
    int f = tid & (H2_ - 1);
    // W2 column f in registers (16 consecutive lanes read 64B -> coalesced;
    // same 2KB table for every thread -> L1-resident)
    float w2c[H1_];
#pragma unroll
    for (int k = 0; k < H1_; ++k) w2c[k] = W2[k * H2_ + f];
    int r = erow[e];
    int c = ecol[e];
    const float4* h1r = reinterpret_cast<const float4*>(h1 + (size_t)c * H1_);
    float acc = 0.f;
#pragma unroll
    for (int k4 = 0; k4 < H1_ / 4; ++k4) {
        float4 v = h1r[k4];            // broadcast within 16-lane group
        acc = fmaf(fmaxf(v.x, 0.f), w2c[k4 * 4 + 0], acc);
        acc = fmaf(fmaxf(v.y, 0.f), w2c[k4 * 4 + 1], acc);
        acc = fmaf(fmaxf(v.z, 0.f), w2c[k4 * 4 + 2], acc);
        acc = fmaf(fmaxf(v.w, 0.f), w2c[k4 * 4 + 3], acc);
    }
    atomicAdd(&z[(size_t)r * H2_ + f], ew[e] * acc);
}

// ---------------- K4: out = z @ z^T  (EXACT R10: 64x256, 8x8/thread) -------
constexpr int BI = 64;
constexpr int BJ = 256;

__global__ __launch_bounds__(256) void zzt(const float* __restrict__ z,
                                           float* __restrict__ out) {
    __shared__ float zi[H2_][BI + 4];    // 16 x 68
    __shared__ float zj[H2_][BJ + 8];    // 16 x 264
    const int t  = threadIdx.x;
    const int ib = blockIdx.y * BI;
    const int jb = blockIdx.x * BJ;

    // stage zi: 64 rows x 16k. thread -> (row = t>>2, kq = (t&3)*4)
    {
        int row = t >> 2;
        int kq  = (t & 3) * 4;
        int gr  = ib + row;
        float4 v = (gr < N_)
            ? *reinterpret_cast<const float4*>(z + (size_t)gr * H2_ + kq)
            : make_float4(0.f, 0.f, 0.f, 0.f);
        zi[kq + 0][row] = v.x;
        zi[kq + 1][row] = v.y;
        zi[kq + 2][row] = v.z;
        zi[kq + 3][row] = v.w;
    }
    // stage zj: 256 rows x 16k, 4 iterations
#pragma unroll
    for (int it = 0; it < 4; ++it) {
        int idx = it * 256 + t;
        int row = idx >> 2;
        int kq  = (idx & 3) * 4;
        int gr  = jb + row;
        float4 v = (gr < N_)
            ? *reinterpret_cast<const float4*>(z + (size_t)gr * H2_ + kq)
            : make_float4(0.f, 0.f, 0.f, 0.f);
        zj[kq + 0][row] = v.x;
        zj[kq + 1][row] = v.y;
        zj[kq + 2][row] = v.z;
        zj[kq + 3][row] = v.w;
    }
    __syncthreads();

    const int tj = t & 31;          // 32 j-lanes
    const int i0 = (t >> 5) * 8;    // 8 i-groups of 8 rows

    float4 accA[8] = {};            // j = jb + tj*4 .. +3
    float4 accB[8] = {};            // j = jb + 128 + tj*4 .. +3

#pragma unroll
    for (int k = 0; k < H2_; ++k) {
        float4 b0 = *reinterpret_cast<const float4*>(&zj[k][tj * 4]);
        float4 b1 = *reinterpret_cast<const float4*>(&zj[k][128 + tj * 4]);
        float4 a0 = *reinterpret_cast<const float4*>(&zi[k][i0]);      // bcast
        float4 a1 = *reinterpret_cast<const float4*>(&zi[k][i0 + 4]);  // bcast
        float av[8] = {a0.x, a0.y, a0.z, a0.w, a1.x, a1.y, a1.z, a1.w};
#pragma unroll
        for (int ii = 0; ii < 8; ++ii) {
            accA[ii].x = fmaf(av[ii], b0.x, accA[ii].x);
            accA[ii].y = fmaf(av[ii], b0.y, accA[ii].y);
            accA[ii].z = fmaf(av[ii], b0.z, accA[ii].z);
            accA[ii].w = fmaf(av[ii], b0.w, accA[ii].w);
            accB[ii].x = fmaf(av[ii], b1.x, accB[ii].x);
            accB[ii].y = fmaf(av[ii], b1.y, accB[ii].y);
            accB[ii].z = fmaf(av[ii], b1.z, accB[ii].z);
            accB[ii].w = fmaf(av[ii], b1.w, accB[ii].w);
        }
    }

    const int j0 = jb + tj * 4;
    const int j1 = jb + 128 + tj * 4;
#pragma unroll
    for (int ii = 0; ii < 8; ++ii) {
        int gi = ib + i0 + ii;
        if (gi >= N_) break;
        float* orow = out + (size_t)gi * N_;
        if (j0 + 3 < N_) {
            f32x4 v = {accA[ii].x, accA[ii].y, accA[ii].z, accA[ii].w};
            __builtin_nontemporal_store(v, reinterpret_cast<f32x4*>(orow + j0));
        } else {
            float a[4] = {accA[ii].x, accA[ii].y, accA[ii].z, accA[ii].w};
            for (int jj = 0; jj < 4; ++jj)
                if (j0 + jj < N_) orow[j0 + jj] = a[jj];
        }
        if (j1 + 3 < N_) {
            f32x4 v = {accB[ii].x, accB[ii].y, accB[ii].z, accB[ii].w};
            __builtin_nontemporal_store(v, reinterpret_cast<f32x4*>(orow + j1));
        } else {
            float b[4] = {accB[ii].x, accB[ii].y, accB[ii].z, accB[ii].w};
            for (int jj = 0; jj < 4; ++jj)
                if (j1 + jj < N_) orow[j1 + jj] = b[jj];
        }
    }
}

extern "C" void kernel_launch(void* const* d_in, const int* in_sizes, int n_in,
                              void* d_out, int out_size, void* d_ws, size_t ws_size,
                              hipStream_t stream) {
    const float* x    = (const float*)d_in[0];
    const float* ew   = (const float*)d_in[1];
    const float* W1   = (const float*)d_in[2];
    const float* W2   = (const float*)d_in[3];
    const int*   erow = (const int*)d_in[4];
    const int*   ecol = (const int*)d_in[5];
    float* out = (float*)d_out;

    // workspace (4B elems): h | h1 | z   (h1,z adjacent -> one zero range)
    float* h  = (float*)d_ws;               // N*H1
    float* h1 = h  + (size_t)N_ * H1_;      // N*H1  (atomic target)
    float* z  = h1 + (size_t)N_ * H1_;      // N*H2  (atomic target)

    gemm_xw1_zero<<<GEMM_BLOCKS + ZERO_BLOCKS, 256, 0, stream>>>(
        x, W1, h, (float4*)h1);
    spmm1_atomic<<<(E_ * H1_ + 255) / 256, 256, 0, stream>>>(h, ew, erow, ecol, h1);
    spmm2_mlp<<<(E_ * H2_ + 255) / 256, 256, 0, stream>>>(h1, W2, ew, erow, ecol, z);

    dim3 grid((N_ + BJ - 1) / BJ, (N_ + BI - 1) / BI);   // 40 x 157
    zzt<<<grid, 256, 0, stream>>>(z, out);
}

// Round 13
// 194.011 us; speedup vs baseline: 1.3384x; 1.1704x over previous
//
#include <hip/hip_runtime.h>

// GCN autoencoder: recon = (Z @ Z^T)
//   h  = X @ W1   (10000x512 @ 512x32)
//   h1 = relu(A @ h);  h2 = h1 @ W2   (fused, h1 stays in LDS)
//   z  = A @ h2
//   out= z @ z^T  (1e8 f32, 400 MB store-bound, ~58 us floor)
//
// R13. MODEL CORRECTION (R6+R7 joint): per-node overhead ~0; front-end EXEC
// is ~98us (gemm 17 + scatter 8 + spmm1_mlp ~55 + spmm2 ~18), zzt(R10) ~97.
// This round: front-end only, zzt EXACT R10.
//  - gemm_xw1: 4 cols/thread -> W1 reads float4-coalesced, 4x fewer vmem.
//  - spmm1_mlp/spmm2: edge lists loaded as int4/float4 (rows 384B-aligned),
//    unroll 8 -> 8 independent h-gathers in flight per iter.

constexpr int N_   = 10000;
constexpr int E_   = 320000;
constexpr int F_   = 512;
constexpr int H1_  = 32;
constexpr int H2_  = 16;
constexpr int CAP_ = 96;   // ELL row capacity; P[Poisson(32) > 96] ~ 3e-20

typedef float f32x4 __attribute__((ext_vector_type(4)));

// ---------------- K1: h = X @ W1 (4 cols/thread), side blocks zero cursor --
constexpr int GEMM_THREADS = N_ * (H1_ / 4);            // 80000
constexpr int GEMM_BLOCKS  = (GEMM_THREADS + 255) / 256; // 313
constexpr int ZERO_BLOCKS  = (N_ + 255) / 256;           // 40

__global__ __launch_bounds__(256) void gemm_xw1_zero(const float* __restrict__ x,
                                                     const float* __restrict__ W1,
                                                     float* __restrict__ h,
                                                     int* __restrict__ cursor) {
    if (blockIdx.x >= GEMM_BLOCKS) {
        int i = (blockIdx.x - GEMM_BLOCKS) * 256 + threadIdx.x;
        if (i < N_) cursor[i] = 0;
        return;
    }
    int tid = blockIdx.x * blockDim.x + threadIdx.x;
    if (tid >= GEMM_THREADS) return;
    int r  = tid >> 3;              // /8
    int cq = (tid & 7) * 4;         // column quad 0,4,...,28
    const float4* xr = reinterpret_cast<const float4*>(x + (size_t)r * F_);
    float4 acc = make_float4(0.f, 0.f, 0.f, 0.f);
#pragma unroll 4
    for (int k4 = 0; k4 < F_ / 4; ++k4) {
        float4 xv = xr[k4];
        int k = k4 * 4;
        float4 w0 = *reinterpret_cast<const float4*>(W1 + (k + 0) * H1_ + cq);
        float4 w1 = *reinterpret_cast<const float4*>(W1 + (k + 1) * H1_ + cq);
        float4 w2 = *reinterpret_cast<const float4*>(W1 + (k + 2) * H1_ + cq);
        float4 w3 = *reinterpret_cast<const float4*>(W1 + (k + 3) * H1_ + cq);
        acc.x = fmaf(xv.x, w0.x, acc.x); acc.y = fmaf(xv.x, w0.y, acc.y);
        acc.z = fmaf(xv.x, w0.z, acc.z); acc.w = fmaf(xv.x, w0.w, acc.w);
        acc.x = fmaf(xv.y, w1.x, acc.x); acc.y = fmaf(xv.y, w1.y, acc.y);
        acc.z = fmaf(xv.y, w1.z, acc.z); acc.w = fmaf(xv.y, w1.w, acc.w);
        acc.x = fmaf(xv.z, w2.x, acc.x); acc.y = fmaf(xv.z, w2.y, acc.y);
        acc.z = fmaf(xv.z, w2.z, acc.z); acc.w = fmaf(xv.z, w2.w, acc.w);
        acc.x = fmaf(xv.w, w3.x, acc.x); acc.y = fmaf(xv.w, w3.y, acc.y);
        acc.z = fmaf(xv.w, w3.z, acc.z); acc.w = fmaf(xv.w, w3.w, acc.w);
    }
    *reinterpret_cast<float4*>(h + (size_t)r * H1_ + cq) = acc;
}

// ---------------- K2: scatter edges into ELL rows ----------------
__global__ __launch_bounds__(256) void scatter_ell(const int* __restrict__ erow,
                                                   const int* __restrict__ ecol,
                                                   const float* __restrict__ ew,
                                                   int* __restrict__ cursor,
                                                   int* __restrict__ cole,
                                                   float* __restrict__ we) {
    int e = blockIdx.x * blockDim.x + threadIdx.x;
    if (e >= E_) return;
    int r = erow[e];
    int p = atomicAdd(&cursor[r], 1);
    if (p < CAP_) {                       // overflow-impossible guard
        size_t idx = (size_t)r * CAP_ + p;
        cole[idx] = ecol[e];
        we[idx]   = ew[e];
    }
}

// ---------------- K3: h2 = relu(A @ h) @ W2  (8 rows / block) --------------
__global__ __launch_bounds__(256) void spmm1_mlp(const float* __restrict__ h,
                                                 const int* __restrict__ cursor,
                                                 const int* __restrict__ cole,
                                                 const float* __restrict__ we,
                                                 const float* __restrict__ W2,
                                                 float* __restrict__ h2) {
    __shared__ float sh1[8][H1_ + 1];
    __shared__ float sW2[H1_ * H2_];
    const int t = threadIdx.x;
    sW2[t]       = W2[t];
    sW2[t + 256] = W2[t + 256];

    const int rl = t >> 5;           // 0..7
    const int f  = t & (H1_ - 1);
    const int r  = blockIdx.x * 8 + rl;
    float acc = 0.f;
    if (r < N_) {
        const int deg = cursor[r];
        const int*   cp = cole + (size_t)r * CAP_;   // 384B-aligned
        const float* wp = we   + (size_t)r * CAP_;
        int p = 0;
        for (; p + 8 <= deg; p += 8) {
            int4   c0 = *reinterpret_cast<const int4*>(cp + p);
            int4   c1 = *reinterpret_cast<const int4*>(cp + p + 4);
            float4 w0 = *reinterpret_cast<const float4*>(wp + p);
            float4 w1 = *reinterpret_cast<const float4*>(wp + p + 4);
            float g0 = h[(size_t)c0.x * H1_ + f];
            float g1 = h[(size_t)c0.y * H1_ + f];
            float g2 = h[(size_t)c0.z * H1_ + f];
            float g3 = h[(size_t)c0.w * H1_ + f];
            float g4 = h[(size_t)c1.x * H1_ + f];
            float g5 = h[(size_t)c1.y * H1_ + f];
            float g6 = h[(size_t)c1.z * H1_ + f];
            float g7 = h[(size_t)c1.w * H1_ + f];
            acc = fmaf(w0.x, g0, acc);
            acc = fmaf(w0.y, g1, acc);
            acc = fmaf(w0.z, g2, acc);
            acc = fmaf(w0.w, g3, acc);
            acc = fmaf(w1.x, g4, acc);
            acc = fmaf(w1.y, g5, acc);
            acc = fmaf(w1.z, g6, acc);
            acc = fmaf(w1.w, g7, acc);
        }
        for (; p < deg; ++p)
            acc = fmaf(wp[p], h[(size_t)cp[p] * H1_ + f], acc);
    }
    sh1[rl][f] = fmaxf(acc, 0.f);     // relu fused here
    __syncthreads();

    if (t < 128) {
        const int r2l = t >> 4;       // 0..7
        const int c   = t & (H2_ - 1);
        const int r2  = blockIdx.x * 8 + r2l;
        if (r2 < N_) {
            float a = 0.f;
#pragma unroll
            for (int k = 0; k < H1_; ++k)
                a = fmaf(sh1[r2l][k], sW2[k * H2_ + c], a);
            h2[(size_t)r2 * H2_ + c] = a;
        }
    }
}

// ---------------- K4: z = A @ h2  (16 rows / block) ----------------
__global__ __launch_bounds__(256) void spmm2(const float* __restrict__ h2,
                                             const int* __restrict__ cursor,
                                             const int* __restrict__ cole,
                                             const float* __restrict__ we,
                                             float* __restrict__ z) {
    const int t = threadIdx.x;
    const int rl = t >> 4;            // 0..15
    const int f  = t & (H2_ - 1);
    const int r  = blockIdx.x * 16 + rl;
    if (r >= N_) return;
    const int deg = cursor[r];
    const int*   cp = cole + (size_t)r * CAP_;
    const float* wp = we   + (size_t)r * CAP_;
    float acc = 0.f;
    int p = 0;
    for (; p + 8 <= deg; p += 8) {
        int4   c0 = *reinterpret_cast<const int4*>(cp + p);
        int4   c1 = *reinterpret_cast<const int4*>(cp + p + 4);
        float4 w0 = *reinterpret_cast<const float4*>(wp + p);
        float4 w1 = *reinterpret_cast<const float4*>(wp + p + 4);
        float g0 = h2[(size_t)c0.x * H2_ + f];
        float g1 = h2[(size_t)c0.y * H2_ + f];
        float g2 = h2[(size_t)c0.z * H2_ + f];
        float g3 = h2[(size_t)c0.w * H2_ + f];
        float g4 = h2[(size_t)c1.x * H2_ + f];
        float g5 = h2[(size_t)c1.y * H2_ + f];
        float g6 = h2[(size_t)c1.z * H2_ + f];
        float g7 = h2[(size_t)c1.w * H2_ + f];
        acc = fmaf(w0.x, g0, acc);
        acc = fmaf(w0.y, g1, acc);
        acc = fmaf(w0.z, g2, acc);
        acc = fmaf(w0.w, g3, acc);
        acc = fmaf(w1.x, g4, acc);
        acc = fmaf(w1.y, g5, acc);
        acc = fmaf(w1.z, g6, acc);
        acc = fmaf(w1.w, g7, acc);
    }
    for (; p < deg; ++p)
        acc = fmaf(wp[p], h2[(size_t)cp[p] * H2_ + f], acc);
    z[(size_t)r * H2_ + f] = acc;
}

// ---------------- K5: out = z @ z^T  (EXACT R10: 64x256, 8x8/thread) -------
constexpr int BI = 64;
constexpr int BJ = 256;

__global__ __launch_bounds__(256) void zzt(const float* __restrict__ z,
                                           float* __restrict__ out) {
    __shared__ float zi[H2_][BI + 4];    // 16 x 68
    __shared__ float zj[H2_][BJ + 8];    // 16 x 264
    const int t  = threadIdx.x;
    const int ib = blockIdx.y * BI;
    const int jb = blockIdx.x * BJ;

    {
        int row = t >> 2;
        int kq  = (t & 3) * 4;
        int gr  = ib + row;
        float4 v = (gr < N_)
            ? *reinterpret_cast<const float4*>(z + (size_t)gr * H2_ + kq)
            : make_float4(0.f, 0.f, 0.f, 0.f);
        zi[kq + 0][row] = v.x;
        zi[kq + 1][row] = v.y;
        zi[kq + 2][row] = v.z;
        zi[kq + 3][row] = v.w;
    }
#pragma unroll
    for (int it = 0; it < 4; ++it) {
        int idx = it * 256 + t;
        int row = idx >> 2;
        int kq  = (idx & 3) * 4;
        int gr  = jb + row;
        float4 v = (gr < N_)
            ? *reinterpret_cast<const float4*>(z + (size_t)gr * H2_ + kq)
            : make_float4(0.f, 0.f, 0.f, 0.f);
        zj[kq + 0][row] = v.x;
        zj[kq + 1][row] = v.y;
        zj[kq + 2][row] = v.z;
        zj[kq + 3][row] = v.w;
    }
    __syncthreads();

    const int tj = t & 31;          // 32 j-lanes
    const int i0 = (t >> 5) * 8;    // 8 i-groups of 8 rows

    float4 accA[8] = {};            // j = jb + tj*4 .. +3
    float4 accB[8] = {};            // j = jb + 128 + tj*4 .. +3

#pragma unroll
    for (int k = 0; k < H2_; ++k) {
        float4 b0 = *reinterpret_cast<const float4*>(&zj[k][tj * 4]);
        float4 b1 = *reinterpret_cast<const float4*>(&zj[k][128 + tj * 4]);
        float4 a0 = *reinterpret_cast<const float4*>(&zi[k][i0]);      // bcast
        float4 a1 = *reinterpret_cast<const float4*>(&zi[k][i0 + 4]);  // bcast
        float av[8] = {a0.x, a0.y, a0.z, a0.w, a1.x, a1.y, a1.z, a1.w};
#pragma unroll
        for (int ii = 0; ii < 8; ++ii) {
            accA[ii].x = fmaf(av[ii], b0.x, accA[ii].x);
            accA[ii].y = fmaf(av[ii], b0.y, accA[ii].y);
            accA[ii].z = fmaf(av[ii], b0.z, accA[ii].z);
            accA[ii].w = fmaf(av[ii], b0.w, accA[ii].w);
            accB[ii].x = fmaf(av[ii], b1.x, accB[ii].x);
            accB[ii].y = fmaf(av[ii], b1.y, accB[ii].y);
            accB[ii].z = fmaf(av[ii], b1.z, accB[ii].z);
            accB[ii].w = fmaf(av[ii], b1.w, accB[ii].w);
        }
    }

    const int j0 = jb + tj * 4;
    const int j1 = jb + 128 + tj * 4;
#pragma unroll
    for (int ii = 0; ii < 8; ++ii) {
        int gi = ib + i0 + ii;
        if (gi >= N_) break;
        float* orow = out + (size_t)gi * N_;
        if (j0 + 3 < N_) {
            f32x4 v = {accA[ii].x, accA[ii].y, accA[ii].z, accA[ii].w};
            __builtin_nontemporal_store(v, reinterpret_cast<f32x4*>(orow + j0));
        } else {
            float a[4] = {accA[ii].x, accA[ii].y, accA[ii].z, accA[ii].w};
            for (int jj = 0; jj < 4; ++jj)
                if (j0 + jj < N_) orow[j0 + jj] = a[jj];
        }
        if (j1 + 3 < N_) {
            f32x4 v = {accB[ii].x, accB[ii].y, accB[ii].z, accB[ii].w};
            __builtin_nontemporal_store(v, reinterpret_cast<f32x4*>(orow + j1));
        } else {
            float b[4] = {accB[ii].x, accB[ii].y, accB[ii].z, accB[ii].w};
            for (int jj = 0; jj < 4; ++jj)
                if (j1 + jj < N_) orow[j1 + jj] = b[jj];
        }
    }
}

extern "C" void kernel_launch(void* const* d_in, const int* in_sizes, int n_in,
                              void* d_out, int out_size, void* d_ws, size_t ws_size,
                              hipStream_t stream) {
    const float* x    = (const float*)d_in[0];
    const float* ew   = (const float*)d_in[1];
    const float* W1   = (const float*)d_in[2];
    const float* W2   = (const float*)d_in[3];
    const int*   erow = (const int*)d_in[4];
    const int*   ecol = (const int*)d_in[5];
    float* out = (float*)d_out;

    // workspace layout (4B elements) — same as R10
    float* h      = (float*)d_ws;              // N*H1
    float* h2     = h  + (size_t)N_ * H1_;     // N*H2
    float* z      = h2 + (size_t)N_ * H2_;     // N*H2
    float* we     = z  + (size_t)N_ * H2_;     // N*CAP
    int*   cole   = (int*)(we + (size_t)N_ * CAP_);   // N*CAP
    int*   cursor = cole + (size_t)N_ * CAP_;  // N

    gemm_xw1_zero<<<GEMM_BLOCKS + ZERO_BLOCKS, 256, 0, stream>>>(x, W1, h, cursor);
    scatter_ell<<<(E_ + 255) / 256, 256, 0, stream>>>(erow, ecol, ew, cursor, cole, we);
    spmm1_mlp<<<(N_ + 7) / 8, 256, 0, stream>>>(h, cursor, cole, we, W2, h2);
    spmm2<<<(N_ + 15) / 16, 256, 0, stream>>>(h2, cursor, cole, we, z);

    dim3 grid((N_ + BJ - 1) / BJ, (N_ + BI - 1) / BI);   // 40 x 157
    zzt<<<grid, 256, 0, stream>>>(z, out);
}